// Round 1
// baseline (779.472 us; speedup 1.0000x reference)
//
#include <hip/hip_runtime.h>
#include <stdint.h>
#include <stddef.h>

typedef __attribute__((ext_vector_type(8))) short short8;
typedef __attribute__((ext_vector_type(4))) float f32x4;

// ---- sizes ----
// x: (8, 64, 32, 32, 96) f32.  NH=4, hd=16, scale = 0.25
// intermediates q,k,v: bf16, per (b,o): layout [ch=d/8][pos][dl=d%8], pos = h*32+w (q,k) or w*32+h (v)
#define PER_BO 98304            // 12 * 8192 ushorts per (b,o)
#define CSTRIDE 8192            // 1024 pos * 8 dl

__device__ __forceinline__ unsigned short f2bf(float f) {
    union { float f; unsigned int u; } v; v.f = f;
    unsigned int r = (v.u + 0x7FFFu + ((v.u >> 16) & 1u)) >> 16;
    return (unsigned short)r;
}

// ============================ Kernel 1: projections ============================
// thread per (b, h, w, d) position; 192 outputs per thread.
__global__ __launch_bounds__(256) void proj_kernel(
    const float* __restrict__ x, const float* __restrict__ w_sr, const float* __restrict__ b_sr,
    const float* __restrict__ Wq, const float* __restrict__ bq,
    const float* __restrict__ Wkv, const float* __restrict__ bkv,
    unsigned short* __restrict__ qb, unsigned short* __restrict__ kb, unsigned short* __restrict__ vb)
{
    __shared__ float Wl[192 * 64];
    __shared__ float bl[192];
    int t = threadIdx.x;
    // stage effective weights: rows 0..63 = Wq; rows 64..191 = Wkv * w_sr[c]
    for (int idx = t; idx < 12288; idx += 256) {
        if (idx < 4096) Wl[idx] = Wq[idx];
        else {
            int c = idx & 63;
            Wl[idx] = Wkv[idx - 4096] * w_sr[c];
        }
    }
    if (t < 192) {
        float s;
        if (t < 64) s = bq[t];
        else {
            s = bkv[t - 64];
            for (int c = 0; c < 64; ++c) s += Wkv[(t - 64) * 64 + c] * b_sr[c];
        }
        bl[t] = s;
    }
    __syncthreads();

    size_t p = (size_t)blockIdx.x * 256 + t;
    int b = (int)(p / 98304);
    int pos = (int)(p % 98304);

    float xr[64];
    const float* xp = x + (size_t)b * 64 * 98304 + pos;
#pragma unroll
    for (int c = 0; c < 64; ++c) xr[c] = xp[(size_t)c * 98304];

    int h = pos / 3072;
    int rem = pos - h * 3072;
    int w = rem / 96;
    int d = rem - w * 96;
    int ch = d >> 3, dl = d & 7;
    size_t qk_off = (size_t)ch * CSTRIDE + (size_t)(h * 32 + w) * 8 + dl;
    size_t v_off  = (size_t)ch * CSTRIDE + (size_t)(w * 32 + h) * 8 + dl;

#pragma unroll 2
    for (int o = 0; o < 192; ++o) {
        float acc = bl[o];
        const float4* wrow = reinterpret_cast<const float4*>(&Wl[o * 64]);
#pragma unroll
        for (int c4 = 0; c4 < 16; ++c4) {
            float4 wv = wrow[c4];
            acc += wv.x * xr[c4 * 4 + 0];
            acc += wv.y * xr[c4 * 4 + 1];
            acc += wv.z * xr[c4 * 4 + 2];
            acc += wv.w * xr[c4 * 4 + 3];
        }
        unsigned short u = f2bf(acc);
        if (o < 64)       qb[(size_t)(b * 64 + o) * PER_BO + qk_off] = u;
        else if (o < 128) kb[(size_t)(b * 64 + (o - 64)) * PER_BO + qk_off] = u;
        else              vb[(size_t)(b * 64 + (o - 128)) * PER_BO + v_off] = u;
    }
}

// ============================ Kernel 2: attention ============================
// one block per (b, n, c) triple. 1024 threads = 16 waves = 4 (h,g)-tiles x 4 d-subgroups.
// LDS layout (bytes):
//   Qs: 0      .. 20480   (8 planes * 1280 ushorts; plane = 32 rows * 40 (pad) ushorts)
//   Ks: 20480  .. 40960
//   Vs: 40960  .. 61440   (pass1: aliased as lred, 4*1056 f32)
//   Ps: 61440  .. 71680   (4 subgroup bufs * 1280 ushorts)
//   Os: 71680  .. 139264  (16 planes * 1056 f32; plane = 32 * 33 pad)
__global__ __launch_bounds__(1024, 4) void attn_kernel(
    const unsigned short* __restrict__ qb, const unsigned short* __restrict__ kb,
    const unsigned short* __restrict__ vb,
    const float* __restrict__ gamma, const float* __restrict__ beta,
    float* __restrict__ out)
{
    extern __shared__ char smem[];
    unsigned short* Qs = (unsigned short*)smem;
    unsigned short* Ks = (unsigned short*)(smem + 20480);
    unsigned short* Vs = (unsigned short*)(smem + 40960);
    unsigned short* Ps = (unsigned short*)(smem + 61440);
    float* Os = (float*)(smem + 71680);
    float* lred = (float*)(smem + 40960);

    int t = threadIdx.x;
    int l = t & 63;
    int wv = t >> 6;
    int tile = wv & 3;
    int hb = tile >> 1, gb = tile & 1;
    int dsub = wv >> 2;
    int lr = l & 15, lk = l >> 4;

    int id = blockIdx.x;
    int b = id >> 6;
    int n = (id >> 4) & 3;
    int oc = id & 63;   // n*16 + c

    const unsigned short* qp = qb + (size_t)(b * 64 + oc) * PER_BO;
    const unsigned short* kp = kb + (size_t)(b * 64 + oc) * PER_BO;
    const unsigned short* vp = vb + (size_t)(b * 64 + oc) * PER_BO;

    // decay for this lane's 4 accumulator positions (C-layout: row = hb*16+lk*4+r, col = gb*16+lr)
    float gm = gamma[n], bt = beta[n];
    float decv[4];
#pragma unroll
    for (int r = 0; r < 4; ++r) {
        int hh = hb * 16 + lk * 4 + r;
        int gg = gb * 16 + lr;
        float dc = 2.0f * fabsf((float)(hh - gg)) * gm + bt;
        float sp = fmaxf(dc, 0.0f) + log1pf(__expf(-fabsf(dc)));
        decv[r] = __expf(-sp);
    }

    const float scale = 0.25f;
    f32x4 zero4 = {0.f, 0.f, 0.f, 0.f};
    float lacc[4] = {0.f, 0.f, 0.f, 0.f};

    int qfoff = (hb * 16 + lr) * 40 + lk * 8;   // A-frag: Q row h, k-slice lk*8 (w)
    int kfoff = (gb * 16 + lr) * 40 + lk * 8;   // B-frag: K row g, k-slice lk*8 (w)
    int stage_base = (t >> 5) * 40 + (t & 31);

    // ---------------- PASS 1: denominators ----------------
    for (int ch = 0; ch < 12; ++ch) {
        __syncthreads();
        {
            uint4 uq = *reinterpret_cast<const uint4*>(qp + (size_t)ch * CSTRIDE + t * 8);
            uint4 uk = *reinterpret_cast<const uint4*>(kp + (size_t)ch * CSTRIDE + t * 8);
            const unsigned short* sq = (const unsigned short*)&uq;
            const unsigned short* sk = (const unsigned short*)&uk;
#pragma unroll
            for (int i = 0; i < 8; ++i) {
                Qs[i * 1280 + stage_base] = sq[i];
                Ks[i * 1280 + stage_base] = sk[i];
            }
        }
        __syncthreads();
#pragma unroll
        for (int rr = 0; rr < 2; ++rr) {
            int dl = dsub * 2 + rr;
            short8 a  = *reinterpret_cast<const short8*>(&Qs[dl * 1280 + qfoff]);
            short8 bf = *reinterpret_cast<const short8*>(&Ks[dl * 1280 + kfoff]);
            f32x4 s = __builtin_amdgcn_mfma_f32_16x16x32_bf16(a, bf, zero4, 0, 0, 0);
#pragma unroll
            for (int r = 0; r < 4; ++r)
                lacc[r] += __expf(s[r] * scale + decv[r]);
        }
    }
    __syncthreads();
#pragma unroll
    for (int r = 0; r < 4; ++r)
        lred[dsub * 1056 + (hb * 16 + lk * 4 + r) * 33 + gb * 16 + lr] = lacc[r];
    __syncthreads();
    float rl[4];
#pragma unroll
    for (int r = 0; r < 4; ++r) {
        int idx = (hb * 16 + lk * 4 + r) * 33 + gb * 16 + lr;
        float sum = lred[idx] + lred[1056 + idx] + lred[2112 + idx] + lred[3168 + idx];
        rl[r] = 1.0f / sum;
    }

    // ---------------- PASS 2: P and O ----------------
    int pfoff = (hb * 16 + lr) * 40 + lk * 8;   // A-frag from P: row h, k = g slice
    int vfoff = (gb * 16 + lr) * 40 + lk * 8;   // B-frag from V: row j (= gb tile), k = g slice

    for (int c2 = 0; c2 < 6; ++c2) {
        for (int sub = 0; sub < 2; ++sub) {
            int ch = c2 * 2 + sub;
            __syncthreads();
            {
                uint4 uq = *reinterpret_cast<const uint4*>(qp + (size_t)ch * CSTRIDE + t * 8);
                uint4 uk = *reinterpret_cast<const uint4*>(kp + (size_t)ch * CSTRIDE + t * 8);
                uint4 uv = *reinterpret_cast<const uint4*>(vp + (size_t)ch * CSTRIDE + t * 8);
                const unsigned short* sq = (const unsigned short*)&uq;
                const unsigned short* sk = (const unsigned short*)&uk;
                const unsigned short* sv = (const unsigned short*)&uv;
#pragma unroll
                for (int i = 0; i < 8; ++i) {
                    Qs[i * 1280 + stage_base] = sq[i];
                    Ks[i * 1280 + stage_base] = sk[i];
                    Vs[i * 1280 + stage_base] = sv[i];
                }
            }
            __syncthreads();
            for (int rr = 0; rr < 2; ++rr) {
                int dl = dsub * 2 + rr;
                short8 a  = *reinterpret_cast<const short8*>(&Qs[dl * 1280 + qfoff]);
                short8 bf = *reinterpret_cast<const short8*>(&Ks[dl * 1280 + kfoff]);
                f32x4 s = __builtin_amdgcn_mfma_f32_16x16x32_bf16(a, bf, zero4, 0, 0, 0);
#pragma unroll
                for (int r = 0; r < 4; ++r) {
                    float pv = __expf(s[r] * scale + decv[r]) * rl[r];
                    Ps[dsub * 1280 + (hb * 16 + lk * 4 + r) * 40 + gb * 16 + lr] = f2bf(pv);
                }
                __syncthreads();
                short8 pa  = *reinterpret_cast<const short8*>(&Ps[dsub * 1280 + pfoff]);
                short8 vbf = *reinterpret_cast<const short8*>(&Vs[dl * 1280 + vfoff]);
                f32x4 o4 = __builtin_amdgcn_mfma_f32_16x16x32_bf16(pa, vbf, zero4, 0, 0, 0);
#pragma unroll
                for (int r = 0; r < 4; ++r)
                    Os[(sub * 8 + dl) * 1056 + (hb * 16 + lk * 4 + r) * 33 + gb * 16 + lr] = o4[r];
                __syncthreads();
            }
        }
        // write out 16 d's: thread t -> (h = t>>5, j = t&31); Os idx = dloc*1056 + t + (t>>5)
        {
            size_t obase = ((size_t)(b * 64 + oc) * 1024 + t) * 96 + c2 * 16;
            int lidx = t + (t >> 5);
#pragma unroll
            for (int q2 = 0; q2 < 4; ++q2) {
                float4 ov;
                ov.x = Os[(q2 * 4 + 0) * 1056 + lidx];
                ov.y = Os[(q2 * 4 + 1) * 1056 + lidx];
                ov.z = Os[(q2 * 4 + 2) * 1056 + lidx];
                ov.w = Os[(q2 * 4 + 3) * 1056 + lidx];
                *reinterpret_cast<float4*>(out + obase + q2 * 4) = ov;
            }
        }
    }
}

extern "C" void kernel_launch(void* const* d_in, const int* in_sizes, int n_in,
                              void* d_out, int out_size, void* d_ws, size_t ws_size,
                              hipStream_t stream) {
    const float* x     = (const float*)d_in[0];
    const float* w_sr  = (const float*)d_in[1];
    const float* b_sr  = (const float*)d_in[2];
    const float* Wq    = (const float*)d_in[3];
    const float* bq    = (const float*)d_in[4];
    const float* Wkv   = (const float*)d_in[5];
    const float* bkv   = (const float*)d_in[6];
    const float* gamma = (const float*)d_in[7];
    const float* beta  = (const float*)d_in[8];
    float* out = (float*)d_out;

    unsigned short* qb = (unsigned short*)d_ws;
    unsigned short* kb = qb + (size_t)50331648;
    unsigned short* vb = kb + (size_t)50331648;

    proj_kernel<<<3072, 256, 0, stream>>>(x, w_sr, b_sr, Wq, bq, Wkv, bkv, qb, kb, vb);

    (void)hipFuncSetAttribute(reinterpret_cast<const void*>(attn_kernel),
                              hipFuncAttributeMaxDynamicSharedMemorySize, 139264);
    attn_kernel<<<512, 1024, 139264, stream>>>(qb, kb, vb, gamma, beta, out);
}

// Round 2
// 497.425 us; speedup vs baseline: 1.5670x; 1.5670x over previous
//
#include <hip/hip_runtime.h>
#include <stdint.h>
#include <stddef.h>

typedef __attribute__((ext_vector_type(8))) short short8;
typedef __attribute__((ext_vector_type(4))) float f32x4;

// ---- sizes ----
// x: (8, 64, 32, 32, 96) f32.  NH=4, hd=16, scale = 0.25
// intermediates q,k,v: bf16, per (b,o): layout [ch=d/8][pos][dl=d%8], pos = h*32+w (q,k) or w*32+h (v)
#define PER_BO 98304            // 12 * 8192 ushorts per (b,o)
#define CSTRIDE 8192            // 1024 pos * 8 dl

__device__ __forceinline__ unsigned short f2bf(float f) {
    union { float f; unsigned int u; } v; v.f = f;
    unsigned int r = (v.u + 0x7FFFu + ((v.u >> 16) & 1u)) >> 16;
    return (unsigned short)r;
}

// ============================ Kernel 1: projection GEMM (MFMA) ============================
// C[192 pos, 192 out] per block = X[192 pos, 64 c] * W_eff[64 c, 192 out]
// block covers 2 full (h,w) d-columns (192 consecutive positions of one b).
// x split hi/lo bf16 (removes x quantization error); W_eff single bf16.
// LDS (dynamic, 79104 B): Xhi[192][68] @0, Xlo[192][68] @26112, Wh[192][68] @52224, bias[192] f32 @78336
__global__ __launch_bounds__(256, 2) void proj_mfma(
    const float* __restrict__ x, const float* __restrict__ w_sr, const float* __restrict__ b_sr,
    const float* __restrict__ Wq, const float* __restrict__ bq,
    const float* __restrict__ Wkv, const float* __restrict__ bkv,
    unsigned short* __restrict__ qb, unsigned short* __restrict__ kb, unsigned short* __restrict__ vb)
{
    extern __shared__ char smem[];
    unsigned short* Xhi = (unsigned short*)smem;
    unsigned short* Xlo = (unsigned short*)(smem + 26112);
    unsigned short* Wh  = (unsigned short*)(smem + 52224);
    float* bl           = (float*)(smem + 78336);

    int t = threadIdx.x;
    int bidx = blockIdx.x;
    int b = bidx >> 9;                 // / 512
    int blk = bidx & 511;
    int hwb = blk * 2;                 // global hw index of first column
    size_t p0 = (size_t)blk * 192;

    // ---- stage effective weights (bf16) ----
    for (int idx = t; idx < 12288; idx += 256) {
        int o = idx >> 6, c = idx & 63;
        float wv = (o < 64) ? Wq[idx] : Wkv[idx - 4096] * w_sr[c];
        Wh[o * 68 + c] = f2bf(wv);
    }
    if (t < 192) {
        float s;
        if (t < 64) s = bq[t];
        else {
            s = bkv[t - 64];
            for (int c = 0; c < 64; ++c) s += Wkv[(t - 64) * 64 + c] * b_sr[c];
        }
        bl[t] = s;
    }

    // ---- stage X (f32 -> hi/lo bf16, transposed to [pos][c]) ----
    const float* xb = x + (size_t)b * 64 * 98304 + p0;
#pragma unroll
    for (int j = 0; j < 12; ++j) {
        int idx4 = t + j * 256;            // float4 index within [64 c][48 quads]
        int c = idx4 / 48;
        int pl4 = (idx4 - c * 48) * 4;
        float4 v4 = *reinterpret_cast<const float4*>(xb + (size_t)c * 98304 + pl4);
        const float* fv = (const float*)&v4;
#pragma unroll
        for (int kk = 0; kk < 4; ++kk) {
            float f = fv[kk];
            unsigned short hi = f2bf(f);
            union { unsigned int u; float ff; } hv; hv.u = (unsigned int)hi << 16;
            unsigned short lo = f2bf(f - hv.ff);
            int pl = pl4 + kk;
            Xhi[pl * 68 + c] = hi;
            Xlo[pl * 68 + c] = lo;
        }
    }
    __syncthreads();

    // ---- MFMA compute + direct epilogue ----
    int l = t & 63;
    int wvi = t >> 6;                      // wave id: owns pos-tiles wvi*3 .. wvi*3+2
    int lr = l & 15, hk = l >> 4;
    f32x4 zero4 = {0.f, 0.f, 0.f, 0.f};

#pragma unroll
    for (int pi = 0; pi < 3; ++pi) {
        int pt = wvi * 3 + pi;
        int prow = pt * 16;
        int arow = (prow + lr) * 68;
        short8 ah0 = *reinterpret_cast<const short8*>(&Xhi[arow + hk * 8]);
        short8 ah1 = *reinterpret_cast<const short8*>(&Xhi[arow + 32 + hk * 8]);
        short8 al0 = *reinterpret_cast<const short8*>(&Xlo[arow + hk * 8]);
        short8 al1 = *reinterpret_cast<const short8*>(&Xlo[arow + 32 + hk * 8]);

        int p_local = prow + hk * 4;       // first of this lane's 4 consecutive positions
        int hw_local = p_local / 96;
        int d = p_local - hw_local * 96;   // d, d+1, d+2, d+3 (within one dl-octet)
        int ch = d >> 3, dlb = d & 7;
        int hw = hwb + hw_local;
        size_t qoff = (size_t)ch * CSTRIDE + (size_t)hw * 8 + dlb;
        size_t voff = (size_t)ch * CSTRIDE + (size_t)((hw & 31) * 32 + (hw >> 5)) * 8 + dlb;

        for (int ot = 0; ot < 12; ++ot) {
            int brow = (ot * 16 + lr) * 68;
            short8 b0 = *reinterpret_cast<const short8*>(&Wh[brow + hk * 8]);
            short8 b1 = *reinterpret_cast<const short8*>(&Wh[brow + 32 + hk * 8]);
            f32x4 acc = __builtin_amdgcn_mfma_f32_16x16x32_bf16(ah0, b0, zero4, 0, 0, 0);
            acc = __builtin_amdgcn_mfma_f32_16x16x32_bf16(ah1, b1, acc, 0, 0, 0);
            acc = __builtin_amdgcn_mfma_f32_16x16x32_bf16(al0, b0, acc, 0, 0, 0);
            acc = __builtin_amdgcn_mfma_f32_16x16x32_bf16(al1, b1, acc, 0, 0, 0);

            int o = ot * 16 + lr;
            float bo = bl[o];
            unsigned int u0 = f2bf(acc[0] + bo);
            unsigned int u1 = f2bf(acc[1] + bo);
            unsigned int u2 = f2bf(acc[2] + bo);
            unsigned int u3 = f2bf(acc[3] + bo);
            uint2 st; st.x = u0 | (u1 << 16); st.y = u2 | (u3 << 16);
            unsigned short* dst;
            if (ot < 4)       dst = qb + (size_t)(b * 64 + o) * PER_BO + qoff;
            else if (ot < 8)  dst = kb + (size_t)(b * 64 + o - 64) * PER_BO + qoff;
            else              dst = vb + (size_t)(b * 64 + o - 128) * PER_BO + voff;
            *reinterpret_cast<uint2*>(dst) = st;
        }
    }
}

// ============================ Kernel 2: attention ============================
// one block per (b, n, c) triple. 1024 threads = 16 waves = 4 (h,g)-tiles x 4 d-subgroups.
__global__ __launch_bounds__(1024, 4) void attn_kernel(
    const unsigned short* __restrict__ qb, const unsigned short* __restrict__ kb,
    const unsigned short* __restrict__ vb,
    const float* __restrict__ gamma, const float* __restrict__ beta,
    float* __restrict__ out)
{
    extern __shared__ char smem[];
    unsigned short* Qs = (unsigned short*)smem;
    unsigned short* Ks = (unsigned short*)(smem + 20480);
    unsigned short* Vs = (unsigned short*)(smem + 40960);
    unsigned short* Ps = (unsigned short*)(smem + 61440);
    float* Os = (float*)(smem + 71680);
    float* lred = (float*)(smem + 40960);

    int t = threadIdx.x;
    int l = t & 63;
    int wv = t >> 6;
    int tile = wv & 3;
    int hb = tile >> 1, gb = tile & 1;
    int dsub = wv >> 2;
    int lr = l & 15, lk = l >> 4;

    int id = blockIdx.x;
    int b = id >> 6;
    int n = (id >> 4) & 3;
    int oc = id & 63;   // n*16 + c

    const unsigned short* qp = qb + (size_t)(b * 64 + oc) * PER_BO;
    const unsigned short* kp = kb + (size_t)(b * 64 + oc) * PER_BO;
    const unsigned short* vp = vb + (size_t)(b * 64 + oc) * PER_BO;

    float gm = gamma[n], bt = beta[n];
    float decv[4];
#pragma unroll
    for (int r = 0; r < 4; ++r) {
        int hh = hb * 16 + lk * 4 + r;
        int gg = gb * 16 + lr;
        float dc = 2.0f * fabsf((float)(hh - gg)) * gm + bt;
        float sp = fmaxf(dc, 0.0f) + log1pf(__expf(-fabsf(dc)));
        decv[r] = __expf(-sp);
    }

    const float scale = 0.25f;
    f32x4 zero4 = {0.f, 0.f, 0.f, 0.f};
    float lacc[4] = {0.f, 0.f, 0.f, 0.f};

    int qfoff = (hb * 16 + lr) * 40 + lk * 8;
    int kfoff = (gb * 16 + lr) * 40 + lk * 8;
    int stage_base = (t >> 5) * 40 + (t & 31);

    // ---------------- PASS 1: denominators ----------------
    for (int ch = 0; ch < 12; ++ch) {
        __syncthreads();
        {
            uint4 uq = *reinterpret_cast<const uint4*>(qp + (size_t)ch * CSTRIDE + t * 8);
            uint4 uk = *reinterpret_cast<const uint4*>(kp + (size_t)ch * CSTRIDE + t * 8);
            const unsigned short* sq = (const unsigned short*)&uq;
            const unsigned short* sk = (const unsigned short*)&uk;
#pragma unroll
            for (int i = 0; i < 8; ++i) {
                Qs[i * 1280 + stage_base] = sq[i];
                Ks[i * 1280 + stage_base] = sk[i];
            }
        }
        __syncthreads();
#pragma unroll
        for (int rr = 0; rr < 2; ++rr) {
            int dl = dsub * 2 + rr;
            short8 a  = *reinterpret_cast<const short8*>(&Qs[dl * 1280 + qfoff]);
            short8 bf = *reinterpret_cast<const short8*>(&Ks[dl * 1280 + kfoff]);
            f32x4 s = __builtin_amdgcn_mfma_f32_16x16x32_bf16(a, bf, zero4, 0, 0, 0);
#pragma unroll
            for (int r = 0; r < 4; ++r)
                lacc[r] += __expf(s[r] * scale + decv[r]);
        }
    }
    __syncthreads();
#pragma unroll
    for (int r = 0; r < 4; ++r)
        lred[dsub * 1056 + (hb * 16 + lk * 4 + r) * 33 + gb * 16 + lr] = lacc[r];
    __syncthreads();
    float rl[4];
#pragma unroll
    for (int r = 0; r < 4; ++r) {
        int idx = (hb * 16 + lk * 4 + r) * 33 + gb * 16 + lr;
        float sum = lred[idx] + lred[1056 + idx] + lred[2112 + idx] + lred[3168 + idx];
        rl[r] = 1.0f / sum;
    }

    // ---------------- PASS 2: P and O ----------------
    int pfoff = (hb * 16 + lr) * 40 + lk * 8;
    int vfoff = (gb * 16 + lr) * 40 + lk * 8;

    for (int c2 = 0; c2 < 6; ++c2) {
        for (int sub = 0; sub < 2; ++sub) {
            int ch = c2 * 2 + sub;
            __syncthreads();
            {
                uint4 uq = *reinterpret_cast<const uint4*>(qp + (size_t)ch * CSTRIDE + t * 8);
                uint4 uk = *reinterpret_cast<const uint4*>(kp + (size_t)ch * CSTRIDE + t * 8);
                uint4 uv = *reinterpret_cast<const uint4*>(vp + (size_t)ch * CSTRIDE + t * 8);
                const unsigned short* sq = (const unsigned short*)&uq;
                const unsigned short* sk = (const unsigned short*)&uk;
                const unsigned short* sv = (const unsigned short*)&uv;
#pragma unroll
                for (int i = 0; i < 8; ++i) {
                    Qs[i * 1280 + stage_base] = sq[i];
                    Ks[i * 1280 + stage_base] = sk[i];
                    Vs[i * 1280 + stage_base] = sv[i];
                }
            }
            __syncthreads();
            for (int rr = 0; rr < 2; ++rr) {
                int dl = dsub * 2 + rr;
                short8 a  = *reinterpret_cast<const short8*>(&Qs[dl * 1280 + qfoff]);
                short8 bf = *reinterpret_cast<const short8*>(&Ks[dl * 1280 + kfoff]);
                f32x4 s = __builtin_amdgcn_mfma_f32_16x16x32_bf16(a, bf, zero4, 0, 0, 0);
#pragma unroll
                for (int r = 0; r < 4; ++r) {
                    float pv = __expf(s[r] * scale + decv[r]) * rl[r];
                    Ps[dsub * 1280 + (hb * 16 + lk * 4 + r) * 40 + gb * 16 + lr] = f2bf(pv);
                }
                __syncthreads();
                short8 pa  = *reinterpret_cast<const short8*>(&Ps[dsub * 1280 + pfoff]);
                short8 vbf = *reinterpret_cast<const short8*>(&Vs[dl * 1280 + vfoff]);
                f32x4 o4 = __builtin_amdgcn_mfma_f32_16x16x32_bf16(pa, vbf, zero4, 0, 0, 0);
#pragma unroll
                for (int r = 0; r < 4; ++r)
                    Os[(sub * 8 + dl) * 1056 + (hb * 16 + lk * 4 + r) * 33 + gb * 16 + lr] = o4[r];
                __syncthreads();
            }
        }
        {
            size_t obase = ((size_t)(b * 64 + oc) * 1024 + t) * 96 + c2 * 16;
            int lidx = t + (t >> 5);
#pragma unroll
            for (int q2 = 0; q2 < 4; ++q2) {
                float4 ov;
                ov.x = Os[(q2 * 4 + 0) * 1056 + lidx];
                ov.y = Os[(q2 * 4 + 1) * 1056 + lidx];
                ov.z = Os[(q2 * 4 + 2) * 1056 + lidx];
                ov.w = Os[(q2 * 4 + 3) * 1056 + lidx];
                *reinterpret_cast<float4*>(out + obase + q2 * 4) = ov;
            }
        }
    }
}

extern "C" void kernel_launch(void* const* d_in, const int* in_sizes, int n_in,
                              void* d_out, int out_size, void* d_ws, size_t ws_size,
                              hipStream_t stream) {
    const float* x     = (const float*)d_in[0];
    const float* w_sr  = (const float*)d_in[1];
    const float* b_sr  = (const float*)d_in[2];
    const float* Wq    = (const float*)d_in[3];
    const float* bq    = (const float*)d_in[4];
    const float* Wkv   = (const float*)d_in[5];
    const float* bkv   = (const float*)d_in[6];
    const float* gamma = (const float*)d_in[7];
    const float* beta  = (const float*)d_in[8];
    float* out = (float*)d_out;

    unsigned short* qb = (unsigned short*)d_ws;
    unsigned short* kb = qb + (size_t)50331648;
    unsigned short* vb = kb + (size_t)50331648;

    (void)hipFuncSetAttribute(reinterpret_cast<const void*>(proj_mfma),
                              hipFuncAttributeMaxDynamicSharedMemorySize, 79104);
    proj_mfma<<<4096, 256, 79104, stream>>>(x, w_sr, b_sr, Wq, bq, Wkv, bkv, qb, kb, vb);

    (void)hipFuncSetAttribute(reinterpret_cast<const void*>(attn_kernel),
                              hipFuncAttributeMaxDynamicSharedMemorySize, 139264);
    attn_kernel<<<512, 1024, 139264, stream>>>(qb, kb, vb, gamma, beta, out);
}

// Round 3
// 428.707 us; speedup vs baseline: 1.8182x; 1.1603x over previous
//
#include <hip/hip_runtime.h>
#include <stdint.h>
#include <stddef.h>

typedef __attribute__((ext_vector_type(8))) short short8;
typedef __attribute__((ext_vector_type(4))) float f32x4;

// ---- sizes ----
// x: (8, 64, 32, 32, 96) f32.  NH=4, hd=16, scale = 0.25
// intermediates q,k,v: bf16, per (b,o): layout [ch=d/8][pos][dl=d%8], pos = h*32+w (q,k) or w*32+h (v)
#define PER_BO 98304            // 12 * 8192 ushorts per (b,o)
#define CSTRIDE 8192            // 1024 pos * 8 dl

__device__ __forceinline__ unsigned short f2bf(float f) {
    union { float f; unsigned int u; } v; v.f = f;
    unsigned int r = (v.u + 0x7FFFu + ((v.u >> 16) & 1u)) >> 16;
    return (unsigned short)r;
}

// ============================ Kernel 1: projection GEMM (MFMA) ============================
// C[192 pos, 192 out] per block = X[192 pos, 64 c] * W_eff[64 c, 192 out]
// A (x) loaded straight from global into registers in MFMA fragment layout (hi/lo bf16 split).
// W staged once in LDS (bf16, XOR-swizzled 16B chunks, conflict-free b128 reads).
// One barrier per block.
__global__ __launch_bounds__(256, 3) void proj_mfma(
    const float* __restrict__ x, const float* __restrict__ w_sr, const float* __restrict__ b_sr,
    const float* __restrict__ Wq, const float* __restrict__ bq,
    const float* __restrict__ Wkv, const float* __restrict__ bkv,
    unsigned short* __restrict__ qb, unsigned short* __restrict__ kb, unsigned short* __restrict__ vb)
{
    __shared__ unsigned short Wh[192 * 64];
    __shared__ float bl[192];

    int t = threadIdx.x;
    int bidx = blockIdx.x;
    int b = bidx >> 9;
    int blk = bidx & 511;

    int l = t & 63;
    int wvi = t >> 6;                  // wave id: owns pos-tiles wvi*3 .. wvi*3+2
    int lr = l & 15, hk = l >> 4;

    // ---- A: load x straight into registers (fragment layout), issue early ----
    // lane needs, per pos-tile pt: pos = pt*16 + lr, c = hk*8 + j (frag0) and 32 + hk*8 + j (frag1)
    const float* xb = x + (size_t)b * 6291456 + (size_t)blk * 192;
    float af[3][16];
#pragma unroll
    for (int pi = 0; pi < 3; ++pi) {
        int pt = wvi * 3 + pi;
        const float* xp = xb + (size_t)(hk * 8) * 98304 + pt * 16 + lr;
#pragma unroll
        for (int j = 0; j < 8; ++j) {
            af[pi][j]     = xp[(size_t)j * 98304];
            af[pi][8 + j] = xp[(size_t)(32 + j) * 98304];
        }
    }

    // ---- stage W_eff (bf16, swizzled): element (o,c) -> Wh[o*64 + ((c>>3)^(o&7))*8 + (c&7)] ----
#pragma unroll
    for (int i = 0; i < 12; ++i) {
        int qi = t + i * 256;          // quad index, 3072 total
        int o = qi >> 4;
        int cq = qi & 15;              // c = cq*4
        int c = cq * 4;
        float4 wv4;
        if (o < 64) wv4 = *reinterpret_cast<const float4*>(Wq + o * 64 + c);
        else {
            wv4 = *reinterpret_cast<const float4*>(Wkv + (o - 64) * 64 + c);
            float4 sr = *reinterpret_cast<const float4*>(w_sr + c);
            wv4.x *= sr.x; wv4.y *= sr.y; wv4.z *= sr.z; wv4.w *= sr.w;
        }
        unsigned int u0 = f2bf(wv4.x) | ((unsigned int)f2bf(wv4.y) << 16);
        unsigned int u1 = f2bf(wv4.z) | ((unsigned int)f2bf(wv4.w) << 16);
        uint2 pk; pk.x = u0; pk.y = u1;
        int sw = (cq >> 1) ^ (o & 7);
        *reinterpret_cast<uint2*>(&Wh[o * 64 + sw * 8 + (cq & 1) * 4]) = pk;
    }
    if (t < 192) {
        float s;
        if (t < 64) s = bq[t];
        else {
            s = bkv[t - 64];
            for (int c = 0; c < 64; ++c) s += Wkv[(t - 64) * 64 + c] * b_sr[c];
        }
        bl[t] = s;
    }
    __syncthreads();

    // ---- convert A to hi/lo bf16 fragments ----
    short8 ah[3][2], al[3][2];
#pragma unroll
    for (int pi = 0; pi < 3; ++pi) {
#pragma unroll
        for (int half = 0; half < 2; ++half) {
            union { unsigned short s[8]; short8 v; } uh, ul;
#pragma unroll
            for (int j = 0; j < 8; ++j) {
                float f = af[pi][half * 8 + j];
                unsigned short hi = f2bf(f);
                union { unsigned int u; float ff; } hv; hv.u = (unsigned int)hi << 16;
                uh.s[j] = hi;
                ul.s[j] = f2bf(f - hv.ff);
            }
            ah[pi][half] = uh.v;
            al[pi][half] = ul.v;
        }
    }

    // ---- per-pt store offsets ----
    size_t qoffs[3], voffs[3];
#pragma unroll
    for (int pi = 0; pi < 3; ++pi) {
        int p0 = (wvi * 3 + pi) * 16 + hk * 4;
        int hwl = p0 / 96;
        int d = p0 - hwl * 96;
        int ch = d >> 3, dlb = d & 7;
        int hw = blk * 2 + hwl;
        qoffs[pi] = (size_t)ch * CSTRIDE + (size_t)hw * 8 + dlb;
        voffs[pi] = (size_t)ch * CSTRIDE + (size_t)((hw & 31) * 32 + (hw >> 5)) * 8 + dlb;
    }

    // ---- bias per lane for each ot ----
    float biasv[12];
#pragma unroll
    for (int ot = 0; ot < 12; ++ot) biasv[ot] = bl[ot * 16 + lr];

    f32x4 zero4 = {0.f, 0.f, 0.f, 0.f};
    int s7 = lr & 7;
    int rowb = 0;   // (ot*16+lr)*64 incrementally

    // ---- main loop: ot outer (B-frags read once), pt inner (A resident) ----
#pragma unroll
    for (int ot = 0; ot < 12; ++ot) {
        int o = ot * 16 + lr;
        const unsigned short* wr = &Wh[o * 64];
        short8 b0 = *reinterpret_cast<const short8*>(wr + ((hk ^ s7) * 8));
        short8 b1 = *reinterpret_cast<const short8*>(wr + (((hk + 4) ^ s7) * 8));
        float bo = biasv[ot];
        unsigned short* basep;
        bool isv = false;
        if (ot < 4)       basep = qb + (size_t)(b * 64 + o) * PER_BO;
        else if (ot < 8)  basep = kb + (size_t)(b * 64 + (o - 64)) * PER_BO;
        else {            basep = vb + (size_t)(b * 64 + (o - 128)) * PER_BO; isv = true; }
#pragma unroll
        for (int pi = 0; pi < 3; ++pi) {
            f32x4 acc = __builtin_amdgcn_mfma_f32_16x16x32_bf16(ah[pi][0], b0, zero4, 0, 0, 0);
            acc = __builtin_amdgcn_mfma_f32_16x16x32_bf16(ah[pi][1], b1, acc, 0, 0, 0);
            acc = __builtin_amdgcn_mfma_f32_16x16x32_bf16(al[pi][0], b0, acc, 0, 0, 0);
            acc = __builtin_amdgcn_mfma_f32_16x16x32_bf16(al[pi][1], b1, acc, 0, 0, 0);
            unsigned int u0 = f2bf(acc[0] + bo);
            unsigned int u1 = f2bf(acc[1] + bo);
            unsigned int u2 = f2bf(acc[2] + bo);
            unsigned int u3 = f2bf(acc[3] + bo);
            uint2 st; st.x = u0 | (u1 << 16); st.y = u2 | (u3 << 16);
            *reinterpret_cast<uint2*>(basep + (isv ? voffs[pi] : qoffs[pi])) = st;
        }
        (void)rowb;
    }
}

// ============================ Kernel 2: attention ============================
// one block per (b, n, c) triple. 1024 threads = 16 waves = 4 (h,g)-tiles x 4 d-subgroups.
__global__ __launch_bounds__(1024, 4) void attn_kernel(
    const unsigned short* __restrict__ qb, const unsigned short* __restrict__ kb,
    const unsigned short* __restrict__ vb,
    const float* __restrict__ gamma, const float* __restrict__ beta,
    float* __restrict__ out)
{
    extern __shared__ char smem[];
    unsigned short* Qs = (unsigned short*)smem;
    unsigned short* Ks = (unsigned short*)(smem + 20480);
    unsigned short* Vs = (unsigned short*)(smem + 40960);
    unsigned short* Ps = (unsigned short*)(smem + 61440);
    float* Os = (float*)(smem + 71680);
    float* lred = (float*)(smem + 40960);

    int t = threadIdx.x;
    int l = t & 63;
    int wv = t >> 6;
    int tile = wv & 3;
    int hb = tile >> 1, gb = tile & 1;
    int dsub = wv >> 2;
    int lr = l & 15, lk = l >> 4;

    int id = blockIdx.x;
    int b = id >> 6;
    int n = (id >> 4) & 3;
    int oc = id & 63;   // n*16 + c

    const unsigned short* qp = qb + (size_t)(b * 64 + oc) * PER_BO;
    const unsigned short* kp = kb + (size_t)(b * 64 + oc) * PER_BO;
    const unsigned short* vp = vb + (size_t)(b * 64 + oc) * PER_BO;

    float gm = gamma[n], bt = beta[n];
    float decv[4];
#pragma unroll
    for (int r = 0; r < 4; ++r) {
        int hh = hb * 16 + lk * 4 + r;
        int gg = gb * 16 + lr;
        float dc = 2.0f * fabsf((float)(hh - gg)) * gm + bt;
        float sp = fmaxf(dc, 0.0f) + log1pf(__expf(-fabsf(dc)));
        decv[r] = __expf(-sp);
    }

    const float scale = 0.25f;
    f32x4 zero4 = {0.f, 0.f, 0.f, 0.f};
    float lacc[4] = {0.f, 0.f, 0.f, 0.f};

    int qfoff = (hb * 16 + lr) * 40 + lk * 8;
    int kfoff = (gb * 16 + lr) * 40 + lk * 8;
    int stage_base = (t >> 5) * 40 + (t & 31);

    // ---------------- PASS 1: denominators ----------------
    for (int ch = 0; ch < 12; ++ch) {
        __syncthreads();
        {
            uint4 uq = *reinterpret_cast<const uint4*>(qp + (size_t)ch * CSTRIDE + t * 8);
            uint4 uk = *reinterpret_cast<const uint4*>(kp + (size_t)ch * CSTRIDE + t * 8);
            const unsigned short* sq = (const unsigned short*)&uq;
            const unsigned short* sk = (const unsigned short*)&uk;
#pragma unroll
            for (int i = 0; i < 8; ++i) {
                Qs[i * 1280 + stage_base] = sq[i];
                Ks[i * 1280 + stage_base] = sk[i];
            }
        }
        __syncthreads();
#pragma unroll
        for (int rr = 0; rr < 2; ++rr) {
            int dl = dsub * 2 + rr;
            short8 a  = *reinterpret_cast<const short8*>(&Qs[dl * 1280 + qfoff]);
            short8 bf = *reinterpret_cast<const short8*>(&Ks[dl * 1280 + kfoff]);
            f32x4 s = __builtin_amdgcn_mfma_f32_16x16x32_bf16(a, bf, zero4, 0, 0, 0);
#pragma unroll
            for (int r = 0; r < 4; ++r)
                lacc[r] += __expf(s[r] * scale + decv[r]);
        }
    }
    __syncthreads();
#pragma unroll
    for (int r = 0; r < 4; ++r)
        lred[dsub * 1056 + (hb * 16 + lk * 4 + r) * 33 + gb * 16 + lr] = lacc[r];
    __syncthreads();
    float rl[4];
#pragma unroll
    for (int r = 0; r < 4; ++r) {
        int idx = (hb * 16 + lk * 4 + r) * 33 + gb * 16 + lr;
        float sum = lred[idx] + lred[1056 + idx] + lred[2112 + idx] + lred[3168 + idx];
        rl[r] = 1.0f / sum;
    }

    // ---------------- PASS 2: P and O ----------------
    int pfoff = (hb * 16 + lr) * 40 + lk * 8;
    int vfoff = (gb * 16 + lr) * 40 + lk * 8;

    for (int c2 = 0; c2 < 6; ++c2) {
        for (int sub = 0; sub < 2; ++sub) {
            int ch = c2 * 2 + sub;
            __syncthreads();
            {
                uint4 uq = *reinterpret_cast<const uint4*>(qp + (size_t)ch * CSTRIDE + t * 8);
                uint4 uk = *reinterpret_cast<const uint4*>(kp + (size_t)ch * CSTRIDE + t * 8);
                uint4 uv = *reinterpret_cast<const uint4*>(vp + (size_t)ch * CSTRIDE + t * 8);
                const unsigned short* sq = (const unsigned short*)&uq;
                const unsigned short* sk = (const unsigned short*)&uk;
                const unsigned short* sv = (const unsigned short*)&uv;
#pragma unroll
                for (int i = 0; i < 8; ++i) {
                    Qs[i * 1280 + stage_base] = sq[i];
                    Ks[i * 1280 + stage_base] = sk[i];
                    Vs[i * 1280 + stage_base] = sv[i];
                }
            }
            __syncthreads();
            for (int rr = 0; rr < 2; ++rr) {
                int dl = dsub * 2 + rr;
                short8 a  = *reinterpret_cast<const short8*>(&Qs[dl * 1280 + qfoff]);
                short8 bf = *reinterpret_cast<const short8*>(&Ks[dl * 1280 + kfoff]);
                f32x4 s = __builtin_amdgcn_mfma_f32_16x16x32_bf16(a, bf, zero4, 0, 0, 0);
#pragma unroll
                for (int r = 0; r < 4; ++r) {
                    float pv = __expf(s[r] * scale + decv[r]) * rl[r];
                    Ps[dsub * 1280 + (hb * 16 + lk * 4 + r) * 40 + gb * 16 + lr] = f2bf(pv);
                }
                __syncthreads();
                short8 pa  = *reinterpret_cast<const short8*>(&Ps[dsub * 1280 + pfoff]);
                short8 vbf = *reinterpret_cast<const short8*>(&Vs[dl * 1280 + vfoff]);
                f32x4 o4 = __builtin_amdgcn_mfma_f32_16x16x32_bf16(pa, vbf, zero4, 0, 0, 0);
#pragma unroll
                for (int r = 0; r < 4; ++r)
                    Os[(sub * 8 + dl) * 1056 + (hb * 16 + lk * 4 + r) * 33 + gb * 16 + lr] = o4[r];
                __syncthreads();
            }
        }
        {
            size_t obase = ((size_t)(b * 64 + oc) * 1024 + t) * 96 + c2 * 16;
            int lidx = t + (t >> 5);
#pragma unroll
            for (int q2 = 0; q2 < 4; ++q2) {
                float4 ov;
                ov.x = Os[(q2 * 4 + 0) * 1056 + lidx];
                ov.y = Os[(q2 * 4 + 1) * 1056 + lidx];
                ov.z = Os[(q2 * 4 + 2) * 1056 + lidx];
                ov.w = Os[(q2 * 4 + 3) * 1056 + lidx];
                *reinterpret_cast<float4*>(out + obase + q2 * 4) = ov;
            }
        }
    }
}

extern "C" void kernel_launch(void* const* d_in, const int* in_sizes, int n_in,
                              void* d_out, int out_size, void* d_ws, size_t ws_size,
                              hipStream_t stream) {
    const float* x     = (const float*)d_in[0];
    const float* w_sr  = (const float*)d_in[1];
    const float* b_sr  = (const float*)d_in[2];
    const float* Wq    = (const float*)d_in[3];
    const float* bq    = (const float*)d_in[4];
    const float* Wkv   = (const float*)d_in[5];
    const float* bkv   = (const float*)d_in[6];
    const float* gamma = (const float*)d_in[7];
    const float* beta  = (const float*)d_in[8];
    float* out = (float*)d_out;

    unsigned short* qb = (unsigned short*)d_ws;
    unsigned short* kb = qb + (size_t)50331648;
    unsigned short* vb = kb + (size_t)50331648;

    proj_mfma<<<4096, 256, 0, stream>>>(x, w_sr, b_sr, Wq, bq, Wkv, bkv, qb, kb, vb);

    (void)hipFuncSetAttribute(reinterpret_cast<const void*>(attn_kernel),
                              hipFuncAttributeMaxDynamicSharedMemorySize, 139264);
    attn_kernel<<<512, 1024, 139264, stream>>>(qb, kb, vb, gamma, beta, out);
}